// Round 1
// baseline (257.165 us; speedup 1.0000x reference)
//
#include <hip/hip_runtime.h>

#define Bn 64
#define Ln 200
#define Dn 256
#define Kn 8
#define LPn 208          // L padded to multiple of 16 for MFMA
#define EPSf 1e-5f
#define SCALEf 0.0625f   // 1/sqrt(256)

typedef short bf16x8 __attribute__((ext_vector_type(8)));
typedef float f32x4  __attribute__((ext_vector_type(4)));

__device__ __forceinline__ unsigned short f2bf(float f) {
    unsigned int u = __builtin_bit_cast(unsigned int, f);
    u += 0x7fffu + ((u >> 16) & 1u);     // RTNE
    return (unsigned short)(u >> 16);
}

__device__ __forceinline__ float wsum(float v) {
    v += __shfl_xor(v, 32, 64);
    v += __shfl_xor(v, 16, 64);
    v += __shfl_xor(v, 8, 64);
    v += __shfl_xor(v, 4, 64);
    v += __shfl_xor(v, 2, 64);
    v += __shfl_xor(v, 1, 64);
    return v;
}

// ---------------- prep: LN(intentions), q rows, W_w -> MFMA-B fragment layout ----------------
// blocks 0..1   : i2hat (8 waves, one per k)
// blocks 2..33  : q (128 waves, one per (s,b))
// blocks 34..65 : wfrag pack (8192 threads, one per (frag,lane))
__global__ __launch_bounds__(256) void kprep(
    const float* __restrict__ intentions, const float* __restrict__ g2, const float* __restrict__ b2,
    const float* __restrict__ loc, const float* __restrict__ glob,
    const float* __restrict__ pos, const float* __restrict__ rou,
    const float* __restrict__ g3, const float* __restrict__ b3,
    const int*   __restrict__ seq_len, const float* __restrict__ Ww,
    float* __restrict__ i2hat, float* __restrict__ q, unsigned short* __restrict__ wfrag)
{
    int blk = blockIdx.x, tid = threadIdx.x;
    int lane = tid & 63;
    if (blk < 2) {
        int k = blk * 4 + (tid >> 6);
        const float4 x4 = *(const float4*)(intentions + k * Dn + lane * 4);
        float x[4] = {x4.x, x4.y, x4.z, x4.w};
        float s1 = x[0] + x[1] + x[2] + x[3];
        float s2 = x[0]*x[0] + x[1]*x[1] + x[2]*x[2] + x[3]*x[3];
        s1 = wsum(s1); s2 = wsum(s2);
        float mu = s1 * (1.0f / Dn);
        float var = s2 * (1.0f / Dn) - mu * mu;
        float rs = rsqrtf(var + EPSf);
        const float4 gg = *(const float4*)(g2 + lane * 4);
        const float4 bb = *(const float4*)(b2 + lane * 4);
        float4 o;
        o.x = (x[0]-mu)*rs*gg.x + bb.x; o.y = (x[1]-mu)*rs*gg.y + bb.y;
        o.z = (x[2]-mu)*rs*gg.z + bb.z; o.w = (x[3]-mu)*rs*gg.w + bb.w;
        *(float4*)(i2hat + k * Dn + lane * 4) = o;
    } else if (blk < 34) {
        int wid = (blk - 2) * 4 + (tid >> 6);        // 0..127
        int s = wid / Bn, b = wid % Bn;
        const float* item = s ? glob : loc;
        int idx = seq_len[b] - 1;
        const float4 x4 = *(const float4*)(item + (b * Ln + idx) * Dn + lane * 4);
        const float4 p4 = *(const float4*)(pos + idx * Dn + lane * 4);
        const float4 r4 = *(const float4*)(rou + lane * 4);
        float x[4] = {x4.x + p4.x + r4.x, x4.y + p4.y + r4.y,
                      x4.z + p4.z + r4.z, x4.w + p4.w + r4.w};
        float s1 = x[0] + x[1] + x[2] + x[3];
        float s2 = x[0]*x[0] + x[1]*x[1] + x[2]*x[2] + x[3]*x[3];
        s1 = wsum(s1); s2 = wsum(s2);
        float mu = s1 * (1.0f / Dn);
        float var = s2 * (1.0f / Dn) - mu * mu;
        float rs = rsqrtf(var + EPSf);
        const float4 gg = *(const float4*)(g3 + lane * 4);
        const float4 bb = *(const float4*)(b3 + lane * 4);
        float4 o;
        o.x = (x[0]-mu)*rs*gg.x + bb.x; o.y = (x[1]-mu)*rs*gg.y + bb.y;
        o.z = (x[2]-mu)*rs*gg.z + bb.z; o.w = (x[3]-mu)*rs*gg.w + bb.w;
        *(float4*)(q + wid * Dn + lane * 4) = o;
    } else {
        // pack W_w into B-operand fragment order for mfma_f32_16x16x32_bf16:
        // B[k][n] = Ww[n][k]; lane holds B[kt*32 + (lane>>4)*8 + j][nt*16 + (lane&15)]
        int gt = (blk - 34) * 256 + tid;             // 0..8191
        int frag = gt >> 6, fl = gt & 63;            // frag = kt*16+nt
        int kt = frag >> 4, nt = frag & 15;
        int d = nt * 16 + (fl & 15);
        int e = kt * 32 + (fl >> 4) * 8;
        const float* src = Ww + d * Dn + e;
        unsigned short tmp[8];
#pragma unroll
        for (int j = 0; j < 8; ++j) tmp[j] = f2bf(src[j]);
        ushort4 lo, hi;
        lo.x = tmp[0]; lo.y = tmp[1]; lo.z = tmp[2]; lo.w = tmp[3];
        hi.x = tmp[4]; hi.y = tmp[5]; hi.z = tmp[6]; hi.w = tmp[7];
        unsigned short* dst = wfrag + (size_t)gt * 8;
        *(ushort4*)(dst) = lo;
        *(ushort4*)(dst + 4) = hi;
    }
}

// ---------------- per-row: stats, score softmax, key_hat(bf16), q.kh ----------------
// one wave per (s,b,l) row, l in [0,LPn); l>=Ln writes zero kh rows (MFMA padding)
__global__ __launch_bounds__(256) void krow(
    const float* __restrict__ loc, const float* __restrict__ glob, const float* __restrict__ pos,
    const float* __restrict__ g1, const float* __restrict__ b1,
    const float* __restrict__ g4, const float* __restrict__ b4,
    const float* __restrict__ i2hat, const float* __restrict__ q,
    float* __restrict__ score, float* __restrict__ stats, float* __restrict__ qkh,
    unsigned short* __restrict__ kh16)
{
    int wid = blockIdx.x * 4 + (threadIdx.x >> 6);
    int lane = threadIdx.x & 63;
    int s = wid / (Bn * LPn);
    int rem = wid % (Bn * LPn);
    int b = rem / LPn, l = rem % LPn;
    unsigned short* khrow = kh16 + ((size_t)(s * Bn + b) * LPn + l) * Dn;
    if (l >= Ln) {
        ushort4 z; z.x = z.y = z.z = z.w = 0;
        *(ushort4*)(khrow + lane * 4) = z;
        return;
    }
    const float* item = s ? glob : loc;
    const float4 x4 = *(const float4*)(item + ((size_t)(b * Ln + l)) * Dn + lane * 4);
    const float4 p4 = *(const float4*)(pos + l * Dn + lane * 4);
    float x[4] = {x4.x, x4.y, x4.z, x4.w};
    float p[4] = {p4.x, p4.y, p4.z, p4.w};

    // item stats (for final LN5)
    float s1 = x[0] + x[1] + x[2] + x[3];
    float s2 = x[0]*x[0] + x[1]*x[1] + x[2]*x[2] + x[3]*x[3];
#pragma unroll
    for (int m = 32; m >= 1; m >>= 1) { s1 += __shfl_xor(s1, m, 64); s2 += __shfl_xor(s2, m, 64); }
    float mu = s1 * (1.0f / Dn);
    float var = s2 * (1.0f / Dn) - mu * mu;
    float rs = rsqrtf(var + EPSf);

    // x1 = LN1(item)
    const float4 gg1 = *(const float4*)(g1 + lane * 4);
    const float4 bb1 = *(const float4*)(b1 + lane * 4);
    float x1[4];
    x1[0] = (x[0]-mu)*rs*gg1.x + bb1.x; x1[1] = (x[1]-mu)*rs*gg1.y + bb1.y;
    x1[2] = (x[2]-mu)*rs*gg1.z + bb1.z; x1[3] = (x[3]-mu)*rs*gg1.w + bb1.w;

    // 8 intention logits
    float lg[Kn];
#pragma unroll
    for (int k = 0; k < Kn; ++k) {
        const float4 iv = *(const float4*)(i2hat + k * Dn + lane * 4);
        float pk = x1[0]*iv.x + x1[1]*iv.y + x1[2]*iv.z + x1[3]*iv.w;
        lg[k] = wsum(pk);
    }
    float mx = -1e30f;
#pragma unroll
    for (int k = 0; k < Kn; ++k) { lg[k] *= SCALEf; mx = fmaxf(mx, lg[k]); }
    float se = 0.f;
    float ex[Kn];
#pragma unroll
    for (int k = 0; k < Kn; ++k) { ex[k] = __expf(lg[k] - mx); se += ex[k]; }
    float inv = 1.0f / se;
    int r = (s * Bn + b) * Ln + l;
    if (lane < Kn) score[(size_t)r * Kn + lane] = ex[lane] * inv;
    if (lane == 0) { stats[2 * (size_t)r] = mu; stats[2 * (size_t)r + 1] = var; }

    // key_hat = LN4(item + pos)
    float y[4] = {x[0]+p[0], x[1]+p[1], x[2]+p[2], x[3]+p[3]};
    float t1 = y[0] + y[1] + y[2] + y[3];
    float t2 = y[0]*y[0] + y[1]*y[1] + y[2]*y[2] + y[3]*y[3];
#pragma unroll
    for (int m = 32; m >= 1; m >>= 1) { t1 += __shfl_xor(t1, m, 64); t2 += __shfl_xor(t2, m, 64); }
    float muy = t1 * (1.0f / Dn);
    float vay = t2 * (1.0f / Dn) - muy * muy;
    float rsy = rsqrtf(vay + EPSf);
    const float4 gg4 = *(const float4*)(g4 + lane * 4);
    const float4 bb4 = *(const float4*)(b4 + lane * 4);
    float kh[4];
    kh[0] = (y[0]-muy)*rsy*gg4.x + bb4.x; kh[1] = (y[1]-muy)*rsy*gg4.y + bb4.y;
    kh[2] = (y[2]-muy)*rsy*gg4.z + bb4.z; kh[3] = (y[3]-muy)*rsy*gg4.w + bb4.w;
    ushort4 kv;
    kv.x = f2bf(kh[0]); kv.y = f2bf(kh[1]); kv.z = f2bf(kh[2]); kv.w = f2bf(kh[3]);
    *(ushort4*)(khrow + lane * 4) = kv;

    // q . key_hat (fp32)
    const float4 qv = *(const float4*)(q + (size_t)(s * Bn + b) * Dn + lane * 4);
    float pq = kh[0]*qv.x + kh[1]*qv.y + kh[2]*qv.z + kh[3]*qv.w;
    pq = wsum(pq);
    if (lane == 0) qkh[r] = pq;
}

// ---------------- GEMM: T = kh @ Ww^T, fused relu + q-dot epilogue -> w logits ----------------
// block = (s,b,half): half0 = rows 0..111 (7 mtiles), half1 = rows 112..207 (6 mtiles)
// wave wv covers d-columns [wv*64, wv*64+64)
__global__ __launch_bounds__(256) void kgemm(
    const unsigned short* __restrict__ kh16, const unsigned short* __restrict__ wfrag,
    const float* __restrict__ q, const float* __restrict__ Wb,
    const float* __restrict__ qkh, float* __restrict__ wlogit)
{
    int blk = blockIdx.x;
    int sb = blk >> 1, half = blk & 1;
    int wv = threadIdx.x >> 6, lane = threadIdx.x & 63;
    int mcount = half ? 6 : 7;
    int rowbase = half * 112;

    f32x4 acc[7][4];
#pragma unroll
    for (int mt = 0; mt < 7; ++mt)
#pragma unroll
        for (int nt = 0; nt < 4; ++nt) { acc[mt][nt][0]=0.f; acc[mt][nt][1]=0.f; acc[mt][nt][2]=0.f; acc[mt][nt][3]=0.f; }

    const unsigned short* abase = kh16 + ((size_t)sb * LPn + rowbase) * Dn;
    int arow = lane & 15;
    int acol = (lane >> 4) * 8;

    for (int kt = 0; kt < 8; ++kt) {
        bf16x8 bf[4];
#pragma unroll
        for (int nt = 0; nt < 4; ++nt)
            bf[nt] = *(const bf16x8*)(wfrag + ((size_t)((kt * 16 + (wv * 4 + nt)) * 64 + lane)) * 8);
        for (int mt = 0; mt < mcount; ++mt) {
            bf16x8 af = *(const bf16x8*)(abase + (size_t)(mt * 16 + arow) * Dn + kt * 32 + acol);
#pragma unroll
            for (int nt = 0; nt < 4; ++nt)
                acc[mt][nt] = __builtin_amdgcn_mfma_f32_16x16x32_bf16(af, bf[nt], acc[mt][nt], 0, 0, 0);
        }
    }

    // epilogue: logit_row += sum_d q[d]*relu(T[row][d] + Wb[d])
    int col = lane & 15, quad = lane >> 4;
    float qv[4], wbv[4];
#pragma unroll
    for (int nt = 0; nt < 4; ++nt) {
        int d = (wv * 4 + nt) * 16 + col;
        qv[nt] = q[(size_t)sb * Dn + d];
        wbv[nt] = Wb[d];
    }
    __shared__ float part[4][112];
    for (int mt = 0; mt < mcount; ++mt) {
#pragma unroll
        for (int j = 0; j < 4; ++j) {
            float t = 0.f;
#pragma unroll
            for (int nt = 0; nt < 4; ++nt) {
                float v = acc[mt][nt][j] + wbv[nt];
                v = fmaxf(v, 0.f);
                t = fmaf(qv[nt], v, t);
            }
            t += __shfl_xor(t, 1, 64);
            t += __shfl_xor(t, 2, 64);
            t += __shfl_xor(t, 4, 64);
            t += __shfl_xor(t, 8, 64);
            if (col == 0) part[wv][mt * 16 + quad * 4 + j] = t;
        }
    }
    __syncthreads();
    int t = threadIdx.x;
    if (t < mcount * 16) {
        int l = rowbase + t;
        if (l < Ln)
            wlogit[(size_t)sb * Ln + l] = qkh[(size_t)sb * Ln + l]
                + part[0][t] + part[1][t] + part[2][t] + part[3][t];
    }
}

// ---------------- softmax over L per (s,b) ----------------
__global__ __launch_bounds__(256) void ksoft(const float* __restrict__ wlogit, float* __restrict__ wsoft)
{
    int sb = blockIdx.x, t = threadIdx.x;
    __shared__ float red[4];
    float lg = (t < Ln) ? wlogit[(size_t)sb * Ln + t] * SCALEf : -1e30f;
    float m = lg;
#pragma unroll
    for (int mk = 32; mk >= 1; mk >>= 1) m = fmaxf(m, __shfl_xor(m, mk, 64));
    if ((t & 63) == 0) red[t >> 6] = m;
    __syncthreads();
    m = fmaxf(fmaxf(red[0], red[1]), fmaxf(red[2], red[3]));
    __syncthreads();
    float ex = (t < Ln) ? __expf(lg - m) : 0.f;
    float sm = ex;
#pragma unroll
    for (int mk = 32; mk >= 1; mk >>= 1) sm += __shfl_xor(sm, mk, 64);
    if ((t & 63) == 0) red[t >> 6] = sm;
    __syncthreads();
    sm = red[0] + red[1] + red[2] + red[3];
    if (t < Ln) wsoft[(size_t)sb * Ln + t] = ex / sm;
}

// ---------------- output: sum of LN5(score*w*item) over both sources ----------------
__global__ __launch_bounds__(256) void kout(
    const float* __restrict__ loc, const float* __restrict__ glob,
    const float* __restrict__ score, const float* __restrict__ stats, const float* __restrict__ wsoft,
    const float* __restrict__ g5, const float* __restrict__ b5, float* __restrict__ out)
{
    int blk = blockIdx.x;
    int b = blk / Ln, l = blk % Ln;
    int d = threadIdx.x;
    size_t base = (size_t)(b * Ln + l) * Dn + d;
    float x0 = loc[base], x1 = glob[base];
    size_t r0 = (size_t)b * Ln + l;
    size_t r1 = (size_t)(Bn + b) * Ln + l;
    float mu0 = stats[2*r0], va0 = stats[2*r0+1];
    float mu1 = stats[2*r1], va1 = stats[2*r1+1];
    float w0 = wsoft[r0], w1 = wsoft[r1];
    float g5d = g5[d], b5d = b5[d];
    float dx0 = x0 - mu0, dx1 = x1 - mu1;
#pragma unroll
    for (int k = 0; k < Kn; ++k) {
        float c0 = score[r0 * Kn + k] * w0;
        float c1 = score[r1 * Kn + k] * w1;
        float a0 = c0 * rsqrtf(c0 * c0 * va0 + EPSf);
        float a1 = c1 * rsqrtf(c1 * c1 * va1 + EPSf);
        out[((size_t)(b * Kn + k) * Ln + l) * Dn + d] = g5d * (a0 * dx0 + a1 * dx1) + 2.0f * b5d;
    }
}

extern "C" void kernel_launch(void* const* d_in, const int* in_sizes, int n_in,
                              void* d_out, int out_size, void* d_ws, size_t ws_size,
                              hipStream_t stream) {
    const float* loc   = (const float*)d_in[0];
    const float* glob  = (const float*)d_in[1];
    const float* inten = (const float*)d_in[2];
    const float* pos   = (const float*)d_in[3];
    const float* rou   = (const float*)d_in[4];
    const float* Ww    = (const float*)d_in[5];
    const float* Wb    = (const float*)d_in[6];
    const float* g1 = (const float*)d_in[7],  *b1 = (const float*)d_in[8];
    const float* g2 = (const float*)d_in[9],  *b2 = (const float*)d_in[10];
    const float* g3 = (const float*)d_in[11], *b3 = (const float*)d_in[12];
    const float* g4 = (const float*)d_in[13], *b4 = (const float*)d_in[14];
    const float* g5 = (const float*)d_in[15], *b5 = (const float*)d_in[16];
    const int* seq_len = (const int*)d_in[17];
    float* out = (float*)d_out;

    char* ws = (char*)d_ws;
    size_t off = 0;
    float* i2hat = (float*)(ws + off);            off += (size_t)Kn * Dn * 4;            // 8 KB
    float* q     = (float*)(ws + off);            off += (size_t)2 * Bn * Dn * 4;        // 128 KB
    unsigned short* wfrag = (unsigned short*)(ws + off); off += (size_t)Dn * Dn * 2;     // 128 KB
    unsigned short* kh16  = (unsigned short*)(ws + off); off += (size_t)2 * Bn * LPn * Dn * 2; // 13.6 MB
    float* score  = (float*)(ws + off);           off += (size_t)2 * Bn * Ln * Kn * 4;   // 819 KB
    float* stats  = (float*)(ws + off);           off += (size_t)2 * Bn * Ln * 2 * 4;    // 410 KB
    float* qkh    = (float*)(ws + off);           off += (size_t)2 * Bn * Ln * 4;        // 205 KB
    float* wlogit = (float*)(ws + off);           off += (size_t)2 * Bn * Ln * 4;        // 205 KB
    float* wsoft  = (float*)(ws + off);           off += (size_t)2 * Bn * Ln * 4;        // 205 KB

    kprep<<<66, 256, 0, stream>>>(inten, g2, b2, loc, glob, pos, rou, g3, b3, seq_len, Ww,
                                  i2hat, q, wfrag);
    krow<<<(2 * Bn * LPn) / 4, 256, 0, stream>>>(loc, glob, pos, g1, b1, g4, b4, i2hat, q,
                                                 score, stats, qkh, kh16);
    kgemm<<<2 * Bn * 2, 256, 0, stream>>>(kh16, wfrag, q, Wb, qkh, wlogit);
    ksoft<<<2 * Bn, 256, 0, stream>>>(wlogit, wsoft);
    kout<<<Bn * Ln, 256, 0, stream>>>(loc, glob, score, stats, wsoft, g5, b5, out);
}

// Round 2
// 200.125 us; speedup vs baseline: 1.2850x; 1.2850x over previous
//
#include <hip/hip_runtime.h>

#define Bn 64
#define Ln 200
#define Dn 256
#define Kn 8
#define LPn 208          // L padded to multiple of 16 for MFMA
#define EPSf 1e-5f
#define SCALEf 0.0625f   // 1/sqrt(256)

typedef short bf16x8 __attribute__((ext_vector_type(8)));
typedef float f32x4  __attribute__((ext_vector_type(4)));

__device__ __forceinline__ unsigned short f2bf(float f) {
    unsigned int u = __builtin_bit_cast(unsigned int, f);
    u += 0x7fffu + ((u >> 16) & 1u);     // RTNE
    return (unsigned short)(u >> 16);
}

__device__ __forceinline__ float wsum(float v) {
    v += __shfl_xor(v, 32, 64);
    v += __shfl_xor(v, 16, 64);
    v += __shfl_xor(v, 8, 64);
    v += __shfl_xor(v, 4, 64);
    v += __shfl_xor(v, 2, 64);
    v += __shfl_xor(v, 1, 64);
    return v;
}

// ---------------- prep: LN(intentions), q rows, W_w -> MFMA-B fragment layout ----------------
__global__ __launch_bounds__(256) void kprep(
    const float* __restrict__ intentions, const float* __restrict__ g2, const float* __restrict__ b2,
    const float* __restrict__ loc, const float* __restrict__ glob,
    const float* __restrict__ pos, const float* __restrict__ rou,
    const float* __restrict__ g3, const float* __restrict__ b3,
    const int*   __restrict__ seq_len, const float* __restrict__ Ww,
    float* __restrict__ i2hat, float* __restrict__ q, unsigned short* __restrict__ wfrag)
{
    int blk = blockIdx.x, tid = threadIdx.x;
    int lane = tid & 63;
    if (blk < 2) {
        int k = blk * 4 + (tid >> 6);
        const float4 x4 = *(const float4*)(intentions + k * Dn + lane * 4);
        float x[4] = {x4.x, x4.y, x4.z, x4.w};
        float s1 = x[0] + x[1] + x[2] + x[3];
        float s2 = x[0]*x[0] + x[1]*x[1] + x[2]*x[2] + x[3]*x[3];
        s1 = wsum(s1); s2 = wsum(s2);
        float mu = s1 * (1.0f / Dn);
        float var = s2 * (1.0f / Dn) - mu * mu;
        float rs = rsqrtf(var + EPSf);
        const float4 gg = *(const float4*)(g2 + lane * 4);
        const float4 bb = *(const float4*)(b2 + lane * 4);
        float4 o;
        o.x = (x[0]-mu)*rs*gg.x + bb.x; o.y = (x[1]-mu)*rs*gg.y + bb.y;
        o.z = (x[2]-mu)*rs*gg.z + bb.z; o.w = (x[3]-mu)*rs*gg.w + bb.w;
        *(float4*)(i2hat + k * Dn + lane * 4) = o;
    } else if (blk < 34) {
        int wid = (blk - 2) * 4 + (tid >> 6);        // 0..127
        int s = wid / Bn, b = wid % Bn;
        const float* item = s ? glob : loc;
        int idx = seq_len[b] - 1;
        const float4 x4 = *(const float4*)(item + (b * Ln + idx) * Dn + lane * 4);
        const float4 p4 = *(const float4*)(pos + idx * Dn + lane * 4);
        const float4 r4 = *(const float4*)(rou + lane * 4);
        float x[4] = {x4.x + p4.x + r4.x, x4.y + p4.y + r4.y,
                      x4.z + p4.z + r4.z, x4.w + p4.w + r4.w};
        float s1 = x[0] + x[1] + x[2] + x[3];
        float s2 = x[0]*x[0] + x[1]*x[1] + x[2]*x[2] + x[3]*x[3];
        s1 = wsum(s1); s2 = wsum(s2);
        float mu = s1 * (1.0f / Dn);
        float var = s2 * (1.0f / Dn) - mu * mu;
        float rs = rsqrtf(var + EPSf);
        const float4 gg = *(const float4*)(g3 + lane * 4);
        const float4 bb = *(const float4*)(b3 + lane * 4);
        float4 o;
        o.x = (x[0]-mu)*rs*gg.x + bb.x; o.y = (x[1]-mu)*rs*gg.y + bb.y;
        o.z = (x[2]-mu)*rs*gg.z + bb.z; o.w = (x[3]-mu)*rs*gg.w + bb.w;
        *(float4*)(q + wid * Dn + lane * 4) = o;
    } else {
        // pack W_w into B-operand fragment order for mfma_f32_16x16x32_bf16
        int gt = (blk - 34) * 256 + tid;             // 0..8191
        int frag = gt >> 6, fl = gt & 63;            // frag = kt*16+nt
        int kt = frag >> 4, nt = frag & 15;
        int d = nt * 16 + (fl & 15);
        int e = kt * 32 + (fl >> 4) * 8;
        const float* src = Ww + d * Dn + e;
        unsigned short tmp[8];
#pragma unroll
        for (int j = 0; j < 8; ++j) tmp[j] = f2bf(src[j]);
        ushort4 lo, hi;
        lo.x = tmp[0]; lo.y = tmp[1]; lo.z = tmp[2]; lo.w = tmp[3];
        hi.x = tmp[4]; hi.y = tmp[5]; hi.z = tmp[6]; hi.w = tmp[7];
        unsigned short* dst = wfrag + (size_t)gt * 8;
        *(ushort4*)(dst) = lo;
        *(ushort4*)(dst + 4) = hi;
    }
}

// ---------------- per-row: stats, score softmax, key_hat(bf16), q.kh ----------------
__global__ __launch_bounds__(256) void krow(
    const float* __restrict__ loc, const float* __restrict__ glob, const float* __restrict__ pos,
    const float* __restrict__ g1, const float* __restrict__ b1,
    const float* __restrict__ g4, const float* __restrict__ b4,
    const float* __restrict__ i2hat, const float* __restrict__ q,
    float* __restrict__ score, float* __restrict__ stats, float* __restrict__ qkh,
    unsigned short* __restrict__ kh16)
{
    int wid = blockIdx.x * 4 + (threadIdx.x >> 6);
    int lane = threadIdx.x & 63;
    int s = wid / (Bn * LPn);
    int rem = wid % (Bn * LPn);
    int b = rem / LPn, l = rem % LPn;
    unsigned short* khrow = kh16 + ((size_t)(s * Bn + b) * LPn + l) * Dn;
    if (l >= Ln) {
        ushort4 z; z.x = z.y = z.z = z.w = 0;
        *(ushort4*)(khrow + lane * 4) = z;
        return;
    }
    const float* item = s ? glob : loc;
    const float4 x4 = *(const float4*)(item + ((size_t)(b * Ln + l)) * Dn + lane * 4);
    const float4 p4 = *(const float4*)(pos + l * Dn + lane * 4);
    float x[4] = {x4.x, x4.y, x4.z, x4.w};
    float p[4] = {p4.x, p4.y, p4.z, p4.w};

    float s1 = x[0] + x[1] + x[2] + x[3];
    float s2 = x[0]*x[0] + x[1]*x[1] + x[2]*x[2] + x[3]*x[3];
#pragma unroll
    for (int m = 32; m >= 1; m >>= 1) { s1 += __shfl_xor(s1, m, 64); s2 += __shfl_xor(s2, m, 64); }
    float mu = s1 * (1.0f / Dn);
    float var = s2 * (1.0f / Dn) - mu * mu;
    float rs = rsqrtf(var + EPSf);

    const float4 gg1 = *(const float4*)(g1 + lane * 4);
    const float4 bb1 = *(const float4*)(b1 + lane * 4);
    float x1[4];
    x1[0] = (x[0]-mu)*rs*gg1.x + bb1.x; x1[1] = (x[1]-mu)*rs*gg1.y + bb1.y;
    x1[2] = (x[2]-mu)*rs*gg1.z + bb1.z; x1[3] = (x[3]-mu)*rs*gg1.w + bb1.w;

    float lg[Kn];
#pragma unroll
    for (int k = 0; k < Kn; ++k) {
        const float4 iv = *(const float4*)(i2hat + k * Dn + lane * 4);
        float pk = x1[0]*iv.x + x1[1]*iv.y + x1[2]*iv.z + x1[3]*iv.w;
        lg[k] = wsum(pk);
    }
    float mx = -1e30f;
#pragma unroll
    for (int k = 0; k < Kn; ++k) { lg[k] *= SCALEf; mx = fmaxf(mx, lg[k]); }
    float se = 0.f;
    float ex[Kn];
#pragma unroll
    for (int k = 0; k < Kn; ++k) { ex[k] = __expf(lg[k] - mx); se += ex[k]; }
    float inv = 1.0f / se;
    int r = (s * Bn + b) * Ln + l;
    if (lane < Kn) score[(size_t)r * Kn + lane] = ex[lane] * inv;
    if (lane == 0) { stats[2 * (size_t)r] = mu; stats[2 * (size_t)r + 1] = var; }

    float y[4] = {x[0]+p[0], x[1]+p[1], x[2]+p[2], x[3]+p[3]};
    float t1 = y[0] + y[1] + y[2] + y[3];
    float t2 = y[0]*y[0] + y[1]*y[1] + y[2]*y[2] + y[3]*y[3];
#pragma unroll
    for (int m = 32; m >= 1; m >>= 1) { t1 += __shfl_xor(t1, m, 64); t2 += __shfl_xor(t2, m, 64); }
    float muy = t1 * (1.0f / Dn);
    float vay = t2 * (1.0f / Dn) - muy * muy;
    float rsy = rsqrtf(vay + EPSf);
    const float4 gg4 = *(const float4*)(g4 + lane * 4);
    const float4 bb4 = *(const float4*)(b4 + lane * 4);
    float kh[4];
    kh[0] = (y[0]-muy)*rsy*gg4.x + bb4.x; kh[1] = (y[1]-muy)*rsy*gg4.y + bb4.y;
    kh[2] = (y[2]-muy)*rsy*gg4.z + bb4.z; kh[3] = (y[3]-muy)*rsy*gg4.w + bb4.w;
    ushort4 kv;
    kv.x = f2bf(kh[0]); kv.y = f2bf(kh[1]); kv.z = f2bf(kh[2]); kv.w = f2bf(kh[3]);
    *(ushort4*)(khrow + lane * 4) = kv;

    const float4 qv = *(const float4*)(q + (size_t)(s * Bn + b) * Dn + lane * 4);
    float pq = kh[0]*qv.x + kh[1]*qv.y + kh[2]*qv.z + kh[3]*qv.w;
    pq = wsum(pq);
    if (lane == 0) qkh[r] = pq;
}

// ---------------- GEMM: T = kh @ Ww^T, fused relu + q-dot epilogue -> w logits ----------------
// grid = 128 sb * 13 mtiles; block = 4 waves; wave wv covers d-columns [wv*64, wv*64+64)
// Each wave: 1 mtile x 4 ntiles x 8 ktiles = 32 MFMAs. 6656 waves total (~26/CU).
__global__ __launch_bounds__(256) void kgemm(
    const unsigned short* __restrict__ kh16, const unsigned short* __restrict__ wfrag,
    const float* __restrict__ q, const float* __restrict__ Wb,
    const float* __restrict__ qkh, float* __restrict__ wlogit)
{
    int blk = blockIdx.x;
    int sb = blk / 13, mt = blk % 13;
    int wv = threadIdx.x >> 6, lane = threadIdx.x & 63;

    f32x4 acc[4];
#pragma unroll
    for (int nt = 0; nt < 4; ++nt) { acc[nt][0]=0.f; acc[nt][1]=0.f; acc[nt][2]=0.f; acc[nt][3]=0.f; }

    int arow = lane & 15;
    int acol = (lane >> 4) * 8;
    const unsigned short* arowp = kh16 + ((size_t)sb * LPn + mt * 16 + arow) * Dn + acol;
    const unsigned short* bbase = wfrag + (size_t)(wv * 4) * 64 * 8 + (size_t)lane * 8;

#pragma unroll
    for (int kt = 0; kt < 8; ++kt) {
        bf16x8 af = *(const bf16x8*)(arowp + kt * 32);
#pragma unroll
        for (int nt = 0; nt < 4; ++nt) {
            bf16x8 bf = *(const bf16x8*)(bbase + ((size_t)(kt * 16 + nt) * 64) * 8);
            acc[nt] = __builtin_amdgcn_mfma_f32_16x16x32_bf16(af, bf, acc[nt], 0, 0, 0);
        }
    }

    // epilogue: partial[row] = sum_d q[d]*relu(T[row][d] + Wb[d]) over this wave's 64 d-cols
    int col = lane & 15, quad = lane >> 4;
    float qv[4], wbv[4];
#pragma unroll
    for (int nt = 0; nt < 4; ++nt) {
        int d = (wv * 4 + nt) * 16 + col;
        qv[nt] = q[(size_t)sb * Dn + d];
        wbv[nt] = Wb[d];
    }
    __shared__ float part[4][16];
#pragma unroll
    for (int j = 0; j < 4; ++j) {
        float t = 0.f;
#pragma unroll
        for (int nt = 0; nt < 4; ++nt) {
            float v = acc[nt][j] + wbv[nt];
            v = fmaxf(v, 0.f);
            t = fmaf(qv[nt], v, t);
        }
        t += __shfl_xor(t, 1, 64);
        t += __shfl_xor(t, 2, 64);
        t += __shfl_xor(t, 4, 64);
        t += __shfl_xor(t, 8, 64);
        if (col == 0) part[wv][quad * 4 + j] = t;
    }
    __syncthreads();
    int t = threadIdx.x;
    if (t < 16) {
        int l = mt * 16 + t;
        if (l < Ln)
            wlogit[(size_t)sb * Ln + l] = qkh[(size_t)sb * Ln + l]
                + part[0][t] + part[1][t] + part[2][t] + part[3][t];
    }
}

// ---------------- softmax over L per (s,b) ----------------
__global__ __launch_bounds__(256) void ksoft(const float* __restrict__ wlogit, float* __restrict__ wsoft)
{
    int sb = blockIdx.x, t = threadIdx.x;
    __shared__ float red[4];
    float lg = (t < Ln) ? wlogit[(size_t)sb * Ln + t] * SCALEf : -1e30f;
    float m = lg;
#pragma unroll
    for (int mk = 32; mk >= 1; mk >>= 1) m = fmaxf(m, __shfl_xor(m, mk, 64));
    if ((t & 63) == 0) red[t >> 6] = m;
    __syncthreads();
    m = fmaxf(fmaxf(red[0], red[1]), fmaxf(red[2], red[3]));
    __syncthreads();
    float ex = (t < Ln) ? __expf(lg - m) : 0.f;
    float sm = ex;
#pragma unroll
    for (int mk = 32; mk >= 1; mk >>= 1) sm += __shfl_xor(sm, mk, 64);
    if ((t & 63) == 0) red[t >> 6] = sm;
    __syncthreads();
    sm = red[0] + red[1] + red[2] + red[3];
    if (t < Ln) wsoft[(size_t)sb * Ln + t] = ex / sm;
}

// ---------------- output: sum of LN5(score*w*item) over both sources ----------------
__global__ __launch_bounds__(256) void kout(
    const float* __restrict__ loc, const float* __restrict__ glob,
    const float* __restrict__ score, const float* __restrict__ stats, const float* __restrict__ wsoft,
    const float* __restrict__ g5, const float* __restrict__ b5, float* __restrict__ out)
{
    int blk = blockIdx.x;
    int b = blk / Ln, l = blk % Ln;
    int d = threadIdx.x;
    size_t base = (size_t)(b * Ln + l) * Dn + d;
    float x0 = loc[base], x1 = glob[base];
    size_t r0 = (size_t)b * Ln + l;
    size_t r1 = (size_t)(Bn + b) * Ln + l;
    float mu0 = stats[2*r0], va0 = stats[2*r0+1];
    float mu1 = stats[2*r1], va1 = stats[2*r1+1];
    float w0 = wsoft[r0], w1 = wsoft[r1];
    float g5d = g5[d], b5d = b5[d];
    float dx0 = x0 - mu0, dx1 = x1 - mu1;
#pragma unroll
    for (int k = 0; k < Kn; ++k) {
        float c0 = score[r0 * Kn + k] * w0;
        float c1 = score[r1 * Kn + k] * w1;
        float a0 = c0 * rsqrtf(c0 * c0 * va0 + EPSf);
        float a1 = c1 * rsqrtf(c1 * c1 * va1 + EPSf);
        out[((size_t)(b * Kn + k) * Ln + l) * Dn + d] = g5d * (a0 * dx0 + a1 * dx1) + 2.0f * b5d;
    }
}

extern "C" void kernel_launch(void* const* d_in, const int* in_sizes, int n_in,
                              void* d_out, int out_size, void* d_ws, size_t ws_size,
                              hipStream_t stream) {
    const float* loc   = (const float*)d_in[0];
    const float* glob  = (const float*)d_in[1];
    const float* inten = (const float*)d_in[2];
    const float* pos   = (const float*)d_in[3];
    const float* rou   = (const float*)d_in[4];
    const float* Ww    = (const float*)d_in[5];
    const float* Wb    = (const float*)d_in[6];
    const float* g1 = (const float*)d_in[7],  *b1 = (const float*)d_in[8];
    const float* g2 = (const float*)d_in[9],  *b2 = (const float*)d_in[10];
    const float* g3 = (const float*)d_in[11], *b3 = (const float*)d_in[12];
    const float* g4 = (const float*)d_in[13], *b4 = (const float*)d_in[14];
    const float* g5 = (const float*)d_in[15], *b5 = (const float*)d_in[16];
    const int* seq_len = (const int*)d_in[17];
    float* out = (float*)d_out;

    char* ws = (char*)d_ws;
    size_t off = 0;
    float* i2hat = (float*)(ws + off);            off += (size_t)Kn * Dn * 4;
    float* q     = (float*)(ws + off);            off += (size_t)2 * Bn * Dn * 4;
    unsigned short* wfrag = (unsigned short*)(ws + off); off += (size_t)Dn * Dn * 2;
    unsigned short* kh16  = (unsigned short*)(ws + off); off += (size_t)2 * Bn * LPn * Dn * 2;
    float* score  = (float*)(ws + off);           off += (size_t)2 * Bn * Ln * Kn * 4;
    float* stats  = (float*)(ws + off);           off += (size_t)2 * Bn * Ln * 2 * 4;
    float* qkh    = (float*)(ws + off);           off += (size_t)2 * Bn * Ln * 4;
    float* wlogit = (float*)(ws + off);           off += (size_t)2 * Bn * Ln * 4;
    float* wsoft  = (float*)(ws + off);           off += (size_t)2 * Bn * Ln * 4;

    kprep<<<66, 256, 0, stream>>>(inten, g2, b2, loc, glob, pos, rou, g3, b3, seq_len, Ww,
                                  i2hat, q, wfrag);
    krow<<<(2 * Bn * LPn) / 4, 256, 0, stream>>>(loc, glob, pos, g1, b1, g4, b4, i2hat, q,
                                                 score, stats, qkh, kh16);
    kgemm<<<128 * 13, 256, 0, stream>>>(kh16, wfrag, q, Wb, qkh, wlogit);
    ksoft<<<2 * Bn, 256, 0, stream>>>(wlogit, wsoft);
    kout<<<Bn * Ln, 256, 0, stream>>>(loc, glob, score, stats, wsoft, g5, b5, out);
}